// Round 5
// baseline (864.456 us; speedup 1.0000x reference)
//
#include <hip/hip_runtime.h>
#include <math.h>

// Problem constants
#define BN 4
#define CC 256
#define HH_ 128
#define WW_ 128
#define HWP (HH_*WW_)           // 16384 pixels
#define TOK (64*HWP)            // 1,048,576 elems per (scale,batch) token matrix

// Workspace layout (~145.4 MB used):
//  qt, kt, vt : bf16 33,554,432 B each
//  aotp: bf16 padded NHWC [4][130][130][256] = 34,611,200 B (1-px zero halo)
//  Sbf : bf16 scale-1/2 score buffer 8,388,608 B
//  wpack: bf16 [256][9][256] 1,179,648 B
//  Wqkv: bf16 [3][256][256] 393,216 B
//  stats(512) S3(16384) rs0(16384) rs1(4096) rs2(1024) fp32 = 153,600 B
// d_out scratch (67 MB, dead until conv writes it):
//  phase A: xt [0,33.5M), yt [33.5M,67M)  (NHWC bf16 inputs for proj)
//  phase B: part [0,33.5M) flash0 fp32 partials; then S2p [0,8M).

typedef __attribute__((ext_vector_type(8))) short bf16x8;
typedef __attribute__((ext_vector_type(4))) float f32x4;

__device__ __forceinline__ float bf2f(unsigned short u) {
    return __uint_as_float(((unsigned)u) << 16);
}
__device__ __forceinline__ unsigned short f2bf(float f) {
    unsigned u = __float_as_uint(f);
    u += 0x7FFF + ((u >> 16) & 1);
    return (unsigned short)(u >> 16);
}
__device__ __forceinline__ float ld1(const float* p) { return *p; }
__device__ __forceinline__ void st1(float* p, float v) { *p = v; }

// ===========================================================================
// GEMM engine (m97 structure): 128x128 tile, BK=64, 256 thr = 4 waves.
// SINGLE-buffered LDS: As/Bs 16 KB each = 32 KB total -> 4-5 blocks/CU.
// Per K-step: barrier -> stage (global_load_lds w16, XOR-swizzled source)
// -> barrier (vmcnt drain) -> MFMA (swizzled ds_read, conflict-free).
// Cross-block co-residency provides the latency hiding (m114/m97), NOT
// in-block dbuf (m132: 64 KB LDS = occupancy cut = regression).
// ===========================================================================
__device__ __forceinline__ void gload16(const void* g, void* l) {
    __builtin_amdgcn_global_load_lds(
        (__attribute__((address_space(1))) void*)(g),
        (__attribute__((address_space(3))) void*)(l), 16, 0, 0);
}

// stage one 128x64 bf16 tile, row-major source with stride strideElems.
__device__ __forceinline__ void stage64(
    const unsigned short* src, size_t strideElems, unsigned short* lds, int t)
{
    #pragma unroll
    for (int k = 0; k < 4; k++) {
        int n = t + k * 256;              // 16B-segment id, 0..1023
        int row = n >> 3, slot = n & 7;
        const char* gp = (const char*)(src + (size_t)row * strideElems)
                       + ((slot ^ (row & 7)) << 4);
        gload16(gp, (char*)lds + n * 16);
    }
}

// stage one 64x64 bf16 tile (half-height).
__device__ __forceinline__ void stage32(
    const unsigned short* src, size_t strideElems, unsigned short* lds, int t)
{
    #pragma unroll
    for (int k = 0; k < 2; k++) {
        int n = t + k * 256;              // 0..511
        int row = n >> 3, slot = n & 7;
        const char* gp = (const char*)(src + (size_t)row * strideElems)
                       + ((slot ^ (row & 7)) << 4);
        gload16(gp, (char*)lds + n * 16);
    }
}

__device__ __forceinline__ void mfma_iter_swz(
    const unsigned short* As, const unsigned short* Bs,
    int wm, int wn, int lr, int quad, f32x4 acc[4][4])
{
    #pragma unroll
    for (int s = 0; s < 2; s++) {
        bf16x8 af[4], bfr[4];
        #pragma unroll
        for (int i = 0; i < 4; i++) {
            int row = wm*64 + i*16 + lr;
            int off = (row << 7) + (s << 6) + (quad << 4);
            af[i] = *(const bf16x8*)((const char*)As + (off ^ ((row & 7) << 4)));
        }
        #pragma unroll
        for (int j = 0; j < 4; j++) {
            int row = wn*64 + j*16 + lr;
            int off = (row << 7) + (s << 6) + (quad << 4);
            bfr[j] = *(const bf16x8*)((const char*)Bs + (off ^ ((row & 7) << 4)));
        }
        #pragma unroll
        for (int i = 0; i < 4; i++)
            #pragma unroll
            for (int j = 0; j < 4; j++)
                acc[i][j] = __builtin_amdgcn_mfma_f32_16x16x32_bf16(
                    af[i], bfr[j], acc[i][j], 0, 0, 0);
    }
}

// ---------------------------------------------------------------------------
__global__ __launch_bounds__(256) void zero_kernel(float* __restrict__ p)
{
    p[blockIdx.x * 256 + threadIdx.x] = 0.f;
}

__global__ __launch_bounds__(256) void zero4(uint4* __restrict__ p, int n4)
{
    uint4 z = make_uint4(0, 0, 0, 0);
    for (int i = blockIdx.x * 256 + threadIdx.x; i < n4; i += gridDim.x * 256)
        p[i] = z;
}

// ---------------------------------------------------------------------------
// NCHW fp32 -> NHWC bf16 for x and y. grid (256 p-tiles, 4 c-tiles, 8)
__global__ __launch_bounds__(256) void nchw_to_nhwc(
    const float* __restrict__ x, const float* __restrict__ y,
    unsigned short* __restrict__ xt, unsigned short* __restrict__ yt)
{
    __shared__ unsigned short T[64 * 72];
    int z = blockIdx.z;
    int b = z & 3, which = z >> 2;
    const float* src = (which ? y : x) + (size_t)b * CC * HWP;
    unsigned short* dst = (which ? yt : xt) + (size_t)b * HWP * CC;
    int p0 = blockIdx.x * 64, c0 = blockIdx.y * 64;
    int t = threadIdx.x;

    int cl = t >> 2, pc = (t & 3) * 16;
    #pragma unroll
    for (int e = 0; e < 16; e += 4) {
        float4 v = *(const float4*)&src[(size_t)(c0 + cl) * HWP + p0 + pc + e];
        T[(pc + e + 0) * 72 + cl] = f2bf(v.x);
        T[(pc + e + 1) * 72 + cl] = f2bf(v.y);
        T[(pc + e + 2) * 72 + cl] = f2bf(v.z);
        T[(pc + e + 3) * 72 + cl] = f2bf(v.w);
    }
    __syncthreads();
    int p = t >> 2, cc = (t & 3) * 16;
    uint4 a = *(uint4*)&T[p * 72 + cc];
    uint4 bsec = *(uint4*)&T[p * 72 + cc + 8];
    uint4* dp = (uint4*)&dst[(size_t)(p0 + p) * CC + c0 + cc];
    dp[0] = a; dp[1] = bsec;
}

// ---------------------------------------------------------------------------
// pack conv weights: Wo [o][c][3][3] fp32 -> wpack [o][tap][c] bf16
__global__ __launch_bounds__(256) void wpack_kernel(
    const float* __restrict__ Wo, unsigned short* __restrict__ wpack)
{
    int o = blockIdx.x, c = threadIdx.x;
    const float* wr = Wo + ((size_t)o * CC + c) * 9;
    #pragma unroll
    for (int tap = 0; tap < 9; tap++)
        wpack[((size_t)o * 9 + tap) * CC + c] = f2bf(wr[tap]);
}

// pack Wq/Wk/Wv fp32 [256][256] -> bf16 [3][256][256]. grid (3)
__global__ __launch_bounds__(256) void wqkv_pack(
    const float* __restrict__ Wq, const float* __restrict__ Wk,
    const float* __restrict__ Wv, unsigned short* __restrict__ Wb)
{
    int which = blockIdx.x;
    const float* W = which == 0 ? Wq : (which == 1 ? Wk : Wv);
    unsigned short* o = Wb + (size_t)which * 65536;
    for (int i = threadIdx.x; i < 65536; i += 256)
        o[i] = f2bf(W[i]);
}

// ---------------------------------------------------------------------------
// proj: C[o][p] = W[o][c] * X[p][c]^T + bias, scattered to token layouts.
// grid: (128 p-tiles, 2 o-tiles, 12) z = which*4 + b.
__global__ __launch_bounds__(256) void proj_gemm(
    const unsigned short* __restrict__ xt, const unsigned short* __restrict__ yt,
    const unsigned short* __restrict__ Wqkv,
    const float* __restrict__ bq, const float* __restrict__ bk,
    const float* __restrict__ bv,
    unsigned short* __restrict__ qt, unsigned short* __restrict__ kt,
    unsigned short* __restrict__ vt)
{
    __shared__ unsigned short As[8192], Bs[8192];
    int z = blockIdx.z, b = z & 3, which = z >> 2;
    const unsigned short* src = (which == 0) ? xt : yt;
    const float* bias = (which == 0) ? bq : (which == 1 ? bk : bv);
    unsigned short* outp = (which == 0) ? qt : (which == 1 ? kt : vt);

    int m0 = blockIdx.y * 128;   // output channels
    int n0 = blockIdx.x * 128;   // pixels
    const unsigned short* A = Wqkv + (size_t)which * 65536 + (size_t)m0 * CC;
    const unsigned short* B = src + ((size_t)b * HWP + n0) * CC;

    int t = threadIdx.x, w = t >> 6, lane = t & 63;
    int quad = lane >> 4, lr = lane & 15, wm = w >> 1, wn = w & 1;

    f32x4 acc[4][4];
    #pragma unroll
    for (int i = 0; i < 4; i++)
        #pragma unroll
        for (int j = 0; j < 4; j++) acc[i][j] = (f32x4){0.f, 0.f, 0.f, 0.f};

    for (int k0 = 0; k0 < CC; k0 += 64) {
        __syncthreads();
        stage64(A + k0, CC, As, t);
        stage64(B + k0, CC, Bs, t);
        __syncthreads();
        mfma_iter_swz(As, Bs, wm, wn, lr, quad, acc);
    }

    #pragma unroll
    for (int i = 0; i < 4; i++) {
        int obase = m0 + wm * 64 + i * 16 + quad * 4;
        #pragma unroll
        for (int rr = 0; rr < 4; rr++) {
            int o = obase + rr;
            int s = o >> 6, lg = s + 1;
            int ch = o & 63;
            float bia = bias[o];
            unsigned short* ob = outp + ((size_t)s * 4 + b) * TOK;
            #pragma unroll
            for (int j = 0; j < 4; j++) {
                int p = n0 + wn * 64 + j * 16 + lr;
                int yy = p >> 7, xx = p & 127;
                int oy = yy >> lg, wy = yy & ((1 << lg) - 1);
                int ox = xx >> lg, wx = xx & ((1 << lg) - 1);
                int tokn = (oy << (7 - lg)) + ox;
                int didx = (ch << (2 * lg)) + (wy << lg) + wx;
                size_t idx;
                if (which == 2)
                    idx = ((size_t)didx << (14 - 2 * lg)) + tokn;   // [d][tok]
                else
                    idx = ((size_t)tokn << (6 + 2 * lg)) + didx;    // [tok][d]
                ob[idx] = f2bf(acc[i][j][rr] + bia);
            }
        }
    }
}

// ---------------------------------------------------------------------------
// Fused scale-0 attention, kv-split x2. 512 thr = 8 waves (wm 0..1 x wn 0..3).
#define PS_STRIDE 136

__global__ __launch_bounds__(512) void flash0(
    const unsigned short* __restrict__ qt, const unsigned short* __restrict__ kt,
    const unsigned short* __restrict__ vt, float* __restrict__ part,
    float* __restrict__ rs0g)
{
    __shared__ unsigned short Ps[64 * PS_STRIDE];   // 17.4 KB
    __shared__ unsigned short Bs[256 * 64];         // 32 KB linear swizzled

    int L = blockIdx.x;
    int xcd = L & 7, slot = L >> 3;
    int b = xcd >> 1;
    int idx = slot + 64 * (xcd & 1);
    int h = idx >> 6;
    int q0 = (idx & 63) * 64;
    int kvbase = h * 2048;

    const unsigned short* Qb = qt + (size_t)b * TOK;
    const unsigned short* Kb = kt + (size_t)b * TOK;
    const unsigned short* Vb = vt + (size_t)b * TOK;

    int t = threadIdx.x, w = t >> 6, lane = t & 63;
    int quad = lane >> 4, lr = lane & 15;
    int wm = w >> 2, wn = w & 3;

    bf16x8 aq[4][2][2];
    #pragma unroll
    for (int k = 0; k < 4; k++)
        #pragma unroll
        for (int s = 0; s < 2; s++)
            #pragma unroll
            for (int i = 0; i < 2; i++)
                aq[k][s][i] = *(const bf16x8*)&Qb[
                    (size_t)(q0 + wm*32 + i*16 + lr) * 256 + k*64 + s*32 + quad*8];

    f32x4 acc_o[2][4];
    #pragma unroll
    for (int i = 0; i < 2; i++)
        #pragma unroll
        for (int j = 0; j < 4; j++) acc_o[i][j] = (f32x4){0.f, 0.f, 0.f, 0.f};
    float rsum[2][4] = {};

    const float SC = 1.f / 16.f;

    for (int kv0 = kvbase; kv0 < kvbase + 2048; kv0 += 128) {
        f32x4 acc_s[2][2];
        #pragma unroll
        for (int i = 0; i < 2; i++)
            #pragma unroll
            for (int j = 0; j < 2; j++) acc_s[i][j] = (f32x4){0.f, 0.f, 0.f, 0.f};

        #pragma unroll
        for (int kp = 0; kp < 2; kp++) {
            __syncthreads();
            #pragma unroll
            for (int k = 0; k < 4; k++) {
                int n = t + k * 512;
                int R = n >> 3, sl = n & 7;
                int kl = R & 127, dsub = R >> 7;
                const char* gp = (const char*)(Kb + (size_t)(kv0 + kl) * 256
                                 + kp*128 + dsub*64) + ((sl ^ (R & 7)) << 4);
                gload16(gp, (char*)Bs + n * 16);
            }
            __syncthreads();
            __builtin_amdgcn_s_setprio(1);
            #pragma unroll
            for (int t2 = 0; t2 < 2; t2++)
                #pragma unroll
                for (int s = 0; s < 2; s++) {
                    bf16x8 bfr[2];
                    #pragma unroll
                    for (int j = 0; j < 2; j++) {
                        int row = t2*128 + wn*32 + j*16 + lr;
                        int off = (row << 7) + (s << 6) + (quad << 4);
                        bfr[j] = *(const bf16x8*)((const char*)Bs
                                   + (off ^ ((row & 7) << 4)));
                    }
                    #pragma unroll
                    for (int i = 0; i < 2; i++)
                        #pragma unroll
                        for (int j = 0; j < 2; j++)
                            acc_s[i][j] = __builtin_amdgcn_mfma_f32_16x16x32_bf16(
                                aq[kp*2 + t2][s][i], bfr[j], acc_s[i][j], 0, 0, 0);
                }
            __builtin_amdgcn_s_setprio(0);
        }

        #pragma unroll
        for (int i = 0; i < 2; i++)
            #pragma unroll
            for (int j = 0; j < 2; j++)
                #pragma unroll
                for (int rr = 0; rr < 4; rr++) {
                    float e = __expf(acc_s[i][j][rr] * SC);
                    Ps[(wm*32 + i*16 + quad*4 + rr) * PS_STRIDE + wn*32 + j*16 + lr]
                        = f2bf(e);
                    rsum[i][rr] += e;
                }

        #pragma unroll
        for (int ks = 0; ks < 2; ks++) {
            __syncthreads();
            #pragma unroll
            for (int k = 0; k < 4; k++) {
                int n = t + k * 512;
                int R = n >> 3, sl = n & 7;
                const char* gp = (const char*)(Vb + (size_t)R * 4096 + kv0 + ks*64)
                               + ((sl ^ (R & 7)) << 4);
                gload16(gp, (char*)Bs + n * 16);
            }
            __syncthreads();
            __builtin_amdgcn_s_setprio(1);
            #pragma unroll
            for (int s = 0; s < 2; s++) {
                bf16x8 pa[2], vb[4];
                #pragma unroll
                for (int i = 0; i < 2; i++)
                    pa[i] = *(const bf16x8*)&Ps[
                        (wm*32 + i*16 + lr) * PS_STRIDE + ks*64 + s*32 + quad*8];
                #pragma unroll
                for (int j = 0; j < 4; j++) {
                    int row = wn*64 + j*16 + lr;
                    int off = (row << 7) + (s << 6) + (quad << 4);
                    vb[j] = *(const bf16x8*)((const char*)Bs
                              + (off ^ ((row & 7) << 4)));
                }
                #pragma unroll
                for (int i = 0; i < 2; i++)
                    #pragma unroll
                    for (int j = 0; j < 4; j++)
                        acc_o[i][j] = __builtin_amdgcn_mfma_f32_16x16x32_bf16(
                            pa[i], vb[j], acc_o[i][j], 0, 0, 0);
            }
            __builtin_amdgcn_s_setprio(0);
        }
    }

    #pragma unroll
    for (int i = 0; i < 2; i++)
        #pragma unroll
        for (int rr = 0; rr < 4; rr++) {
            float v = rsum[i][rr];
            v += __shfl_xor(v, 1); v += __shfl_xor(v, 2);
            v += __shfl_xor(v, 4); v += __shfl_xor(v, 8);
            if (lr == 0)
                atomicAdd(&rs0g[b * 4096 + q0 + wm*32 + i*16 + quad*4 + rr], v);
        }
    float* op = part + ((size_t)(h * 4 + b)) * TOK;
    #pragma unroll
    for (int i = 0; i < 2; i++)
        #pragma unroll
        for (int rr = 0; rr < 4; rr++) {
            int tokl = wm*32 + i*16 + quad*4 + rr;
            float* orow = op + (size_t)(q0 + tokl) * 256;
            #pragma unroll
            for (int j = 0; j < 4; j++)
                orow[wn*64 + j*16 + lr] = acc_o[i][j][rr];
        }
}

// ---------------------------------------------------------------------------
// Sum 2 kv-half partials, divide by rowsum, scatter padded NHWC. grid (256,4).
__global__ __launch_bounds__(256) void combine0f(
    const float* __restrict__ part, const float* __restrict__ rs,
    unsigned short* __restrict__ aotp)
{
    int b = blockIdx.y;
    int tok0 = blockIdx.x * 16;
    const float* p0 = part + (size_t)b * TOK;
    const float* p1 = part + (size_t)(4 + b) * TOK;
    int t = threadIdx.x;
    int w = t >> 6, ch = t & 63;
    int wy = w >> 1, wx = w & 1;
    #pragma unroll 4
    for (int u = 0; u < 16; u++) {
        int tok = tok0 + u;
        size_t base = (size_t)tok * 256 + ch * 4 + w;
        float v = (p0[base] + p1[base]) * (1.f / rs[b * 4096 + tok]);
        int oy = tok >> 6, ox = tok & 63;
        int yy = oy * 2 + wy, xx = ox * 2 + wx;
        aotp[((size_t)(b * 130 + yy + 1) * 130 + xx + 1) * CC + ch] = f2bf(v);
    }
}

// ---------------------------------------------------------------------------
// E = exp(sc * Q K^T) + rowsum atomics. Scale 1.
template<int NTOK, int DD>
__global__ __launch_bounds__(256) void s_gemm_exp(
    const unsigned short* __restrict__ Qb, const unsigned short* __restrict__ Kb,
    unsigned short* __restrict__ S0, float* __restrict__ rsg, float sc)
{
    __shared__ unsigned short As[8192], Bs[8192];
    int bz = blockIdx.z;
    int m0 = blockIdx.y * 128, n0 = blockIdx.x * 128;
    const unsigned short* Q = Qb + (size_t)bz * TOK + (size_t)m0 * DD;
    const unsigned short* K = Kb + (size_t)bz * TOK + (size_t)n0 * DD;
    unsigned short* S = S0 + (size_t)bz * NTOK * NTOK;
    float* rs = rsg + (size_t)bz * NTOK;

    int t = threadIdx.x, w = t >> 6, lane = t & 63;
    int quad = lane >> 4, lr = lane & 15, wm = w >> 1, wn = w & 1;

    f32x4 acc[4][4];
    #pragma unroll
    for (int i = 0; i < 4; i++)
        #pragma unroll
        for (int j = 0; j < 4; j++) acc[i][j] = (f32x4){0.f, 0.f, 0.f, 0.f};

    for (int k0 = 0; k0 < DD; k0 += 64) {
        __syncthreads();
        stage64(Q + k0, DD, As, t);
        stage64(K + k0, DD, Bs, t);
        __syncthreads();
        mfma_iter_swz(As, Bs, wm, wn, lr, quad, acc);
    }

    #pragma unroll
    for (int i = 0; i < 4; i++) {
        int m = m0 + wm * 64 + i * 16 + quad * 4;
        float rsum[4] = {0.f, 0.f, 0.f, 0.f};
        #pragma unroll
        for (int j = 0; j < 4; j++) {
            int n = n0 + wn * 64 + j * 16 + lr;
            #pragma unroll
            for (int rr = 0; rr < 4; rr++) {
                float e = __expf(acc[i][j][rr] * sc);
                S[(size_t)(m + rr) * NTOK + n] = f2bf(e);
                rsum[rr] += e;
            }
        }
        #pragma unroll
        for (int rr = 0; rr < 4; rr++) {
            float v = rsum[rr];
            v += __shfl_xor(v, 1);
            v += __shfl_xor(v, 2);
            v += __shfl_xor(v, 4);
            v += __shfl_xor(v, 8);
            if (lr == 0) atomicAdd(&rs[m + rr], v);
        }
    }
}

// ---------------------------------------------------------------------------
// O = E V (V [d][tok]); divide by rowsum; padded NHWC scatter. Scales 1,2.
template<int NTOK, int DD, int LG, int CH0>
__global__ __launch_bounds__(256) void o_gemm(
    const unsigned short* __restrict__ Pb, const unsigned short* __restrict__ Vb,
    const float* __restrict__ rsg, unsigned short* __restrict__ aotp, int b0)
{
    __shared__ unsigned short As[8192], Bs[8192];
    int bz = blockIdx.z, b = b0 + bz;
    int m0 = blockIdx.y * 128, n0 = blockIdx.x * 128;
    const unsigned short* P = Pb + (size_t)bz * NTOK * NTOK + (size_t)m0 * NTOK;
    const unsigned short* V = Vb + (size_t)bz * TOK + (size_t)n0 * NTOK;
    const float* rs = rsg + (size_t)bz * NTOK;

    int t = threadIdx.x, w = t >> 6, lane = t & 63;
    int quad = lane >> 4, lr = lane & 15, wm = w >> 1, wn = w & 1;

    f32x4 acc[4][4];
    #pragma unroll
    for (int i = 0; i < 4; i++)
        #pragma unroll
        for (int j = 0; j < 4; j++) acc[i][j] = (f32x4){0.f, 0.f, 0.f, 0.f};

    for (int k0 = 0; k0 < NTOK; k0 += 64) {
        __syncthreads();
        stage64(P + k0, NTOK, As, t);
        stage64(V + k0, NTOK, Bs, t);
        __syncthreads();
        mfma_iter_swz(As, Bs, wm, wn, lr, quad, acc);
    }

    #pragma unroll
    for (int i = 0; i < 4; i++) {
        int tb0 = m0 + wm * 64 + i * 16 + quad * 4;
        #pragma unroll
        for (int rr = 0; rr < 4; rr++) {
            int tokn = tb0 + rr;
            float inv = 1.f / rs[tokn];
            int oy = tokn >> (7 - LG), ox = tokn & ((1 << (7 - LG)) - 1);
            #pragma unroll
            for (int j = 0; j < 4; j++) {
                int d = n0 + wn * 64 + j * 16 + lr;
                int ch = d >> (2 * LG);
                int r2 = d & ((1 << (2 * LG)) - 1);
                int wy = r2 >> LG, wx = r2 & ((1 << LG) - 1);
                int yy = (oy << LG) + wy, xx = (ox << LG) + wx;
                aotp[((size_t)(b * 130 + yy + 1) * 130 + xx + 1) * CC + CH0 + ch] =
                    f2bf(acc[i][j][rr] * inv);
            }
        }
    }
}

// ---------------------------------------------------------------------------
// Scale-2 score GEMM, 8-way K-split, fp32 partials. grid (2,2,32).
__global__ __launch_bounds__(256) void s2_partial(
    const unsigned short* __restrict__ Qb, const unsigned short* __restrict__ Kb,
    float* __restrict__ S2p)
{
    __shared__ unsigned short As[8192], Bs[8192];
    int z = blockIdx.z, b = z >> 3, sp = z & 7;
    int m0 = blockIdx.y * 128, n0 = blockIdx.x * 128;
    const unsigned short* Q = Qb + (size_t)b * TOK + (size_t)m0 * 4096 + sp * 512;
    const unsigned short* K = Kb + (size_t)b * TOK + (size_t)n0 * 4096 + sp * 512;
    float* So = S2p + ((size_t)(sp * 4 + b)) * 65536;

    int t = threadIdx.x, w = t >> 6, lane = t & 63;
    int quad = lane >> 4, lr = lane & 15, wm = w >> 1, wn = w & 1;

    f32x4 acc[4][4];
    #pragma unroll
    for (int i = 0; i < 4; i++)
        #pragma unroll
        for (int j = 0; j < 4; j++) acc[i][j] = (f32x4){0.f, 0.f, 0.f, 0.f};

    for (int k0 = 0; k0 < 512; k0 += 64) {
        __syncthreads();
        stage64(Q + k0, 4096, As, t);
        stage64(K + k0, 4096, Bs, t);
        __syncthreads();
        mfma_iter_swz(As, Bs, wm, wn, lr, quad, acc);
    }

    #pragma unroll
    for (int i = 0; i < 4; i++) {
        int m = m0 + wm * 64 + i * 16 + quad * 4;
        #pragma unroll
        for (int j = 0; j < 4; j++) {
            int n = n0 + wn * 64 + j * 16 + lr;
            #pragma unroll
            for (int rr = 0; rr < 4; rr++)
                So[(size_t)(m + rr) * 256 + n] = acc[i][j][rr];
        }
    }
}

// Sum 8 partials, exp, write bf16 S + rowsum. grid (256 rows, 4 b).
__global__ __launch_bounds__(256) void s2_finish(
    const float* __restrict__ S2p, unsigned short* __restrict__ Sbf,
    float* __restrict__ rs2, float sc)
{
    int row = blockIdx.x, b = blockIdx.y, t = threadIdx.x;
    float v = 0.f;
    #pragma unroll
    for (int sp = 0; sp < 8; sp++)
        v += S2p[((size_t)(sp * 4 + b)) * 65536 + row * 256 + t];
    float e = __expf(v * sc);
    Sbf[((size_t)b * 65536) + row * 256 + t] = f2bf(e);
    __shared__ float red[256];
    red[t] = e; __syncthreads();
    for (int s = 128; s > 0; s >>= 1) {
        if (t < s) red[t] += red[t + s];
        __syncthreads();
    }
    if (t == 0) rs2[b * 256 + row] = red[0];
}

// ---------------------------------------------------------------------------
// conv3x3 on padded NHWC (no boundary branches) + fused BN-stats partials.
// grid: (128 y-rows, 2 o-tiles, 4 b). K = 9 taps x 4 c-chunks = 36 steps.
// Single-buffered 32 KB LDS -> 4 blocks/CU, whole grid co-resident.
__global__ __launch_bounds__(256) void conv_gemm(
    const unsigned short* __restrict__ aotp, const unsigned short* __restrict__ wpack,
    const float* __restrict__ bo, float* __restrict__ zout,
    float* __restrict__ stats)
{
    __shared__ unsigned short As[8192], Bs[8192];
    int yrow = blockIdx.x;
    int o0 = blockIdx.y * 128;
    int b = blockIdx.z;
    const unsigned short* aob = aotp + (size_t)b * 130 * 130 * 256;
    const unsigned short* wsrc = wpack + (size_t)o0 * 2304;

    int t = threadIdx.x, w = t >> 6, lane = t & 63;
    int quad = lane >> 4, lr = lane & 15, wm = w >> 1, wn = w & 1;

    f32x4 acc[4][4];
    #pragma unroll
    for (int i = 0; i < 4; i++)
        #pragma unroll
        for (int j = 0; j < 4; j++) acc[i][j] = (f32x4){0.f, 0.f, 0.f, 0.f};

    for (int kk = 0; kk < 36; kk++) {
        int tap = kk >> 2, cb = (kk & 3) * 64;
        int dy = tap / 3 - 1, dx = tap % 3 - 1;
        __syncthreads();
        stage64(wsrc + tap * 256 + cb, 2304, As, t);
        stage64(aob + ((size_t)(yrow + dy + 1) * 130 + (dx + 1)) * 256 + cb, 256,
                Bs, t);
        __syncthreads();
        mfma_iter_swz(As, Bs, wm, wn, lr, quad, acc);
    }

    #pragma unroll
    for (int i = 0; i < 4; i++) {
        #pragma unroll
        for (int rr = 0; rr < 4; rr++) {
            int o = o0 + wm * 64 + i * 16 + quad * 4 + rr;
            float bia = bo[o];
            float s1 = 0.f, s2v = 0.f;
            #pragma unroll
            for (int j = 0; j < 4; j++) {
                int x = wn * 64 + j * 16 + lr;
                float v = acc[i][j][rr] + bia;
                zout[((size_t)(b * CC + o)) * HWP + yrow * WW_ + x] = v;
                s1 += v; s2v = fmaf(v, v, s2v);
            }
            s1 += __shfl_xor(s1, 1); s2v += __shfl_xor(s2v, 1);
            s1 += __shfl_xor(s1, 2); s2v += __shfl_xor(s2v, 2);
            s1 += __shfl_xor(s1, 4); s2v += __shfl_xor(s2v, 4);
            s1 += __shfl_xor(s1, 8); s2v += __shfl_xor(s2v, 8);
            if (lr == 0) {
                atomicAdd(&stats[o], s1);
                atomicAdd(&stats[CC + o], s2v);
            }
        }
    }
}

// ---------------------------------------------------------------------------
// scale-3 S via MFMA: 64x64, K=16384 (16-way split x 1024), atomic fp32 acc.
// grid (64): b = z>>4, kc = z&15. 4 waves, 32x32 quadrants.
__global__ __launch_bounds__(256) void s3_mfma(
    const unsigned short* __restrict__ Qb, const unsigned short* __restrict__ Kb,
    float* __restrict__ S, float sc)
{
    __shared__ unsigned short As[4096], Bs[4096];
    int z = blockIdx.x, b = z >> 4, kc = z & 15;
    const unsigned short* Q = Qb + (size_t)b * TOK + kc * 1024;
    const unsigned short* K = Kb + (size_t)b * TOK + kc * 1024;
    float* Sb = S + (size_t)b * 4096;

    int t = threadIdx.x, w = t >> 6, lane = t & 63;
    int quad = lane >> 4, lr = lane & 15, wm = w >> 1, wn = w & 1;

    f32x4 acc[2][2];
    #pragma unroll
    for (int i = 0; i < 2; i++)
        #pragma unroll
        for (int j = 0; j < 2; j++) acc[i][j] = (f32x4){0.f, 0.f, 0.f, 0.f};

    for (int k0 = 0; k0 < 1024; k0 += 64) {
        __syncthreads();
        stage32(Q + k0, 16384, As, t);
        stage32(K + k0, 16384, Bs, t);
        __syncthreads();
        #pragma unroll
        for (int s = 0; s < 2; s++) {
            bf16x8 af[2], bfr[2];
            #pragma unroll
            for (int i = 0; i < 2; i++) {
                int row = wm*32 + i*16 + lr;
                int off = (row << 7) + (s << 6) + (quad << 4);
                af[i] = *(const bf16x8*)((const char*)As
                          + (off ^ ((row & 7) << 4)));
            }
            #pragma unroll
            for (int j = 0; j < 2; j++) {
                int row = wn*32 + j*16 + lr;
                int off = (row << 7) + (s << 6) + (quad << 4);
                bfr[j] = *(const bf16x8*)((const char*)Bs
                           + (off ^ ((row & 7) << 4)));
            }
            #pragma unroll
            for (int i = 0; i < 2; i++)
                #pragma unroll
                for (int j = 0; j < 2; j++)
                    acc[i][j] = __builtin_amdgcn_mfma_f32_16x16x32_bf16(
                        af[i], bfr[j], acc[i][j], 0, 0, 0);
        }
    }

    #pragma unroll
    for (int i = 0; i < 2; i++)
        #pragma unroll
        for (int j = 0; j < 2; j++)
            #pragma unroll
            for (int rr = 0; rr < 4; rr++)
                atomicAdd(&Sb[(size_t)(wm*32 + i*16 + quad*4 + rr) * 64
                              + wn*32 + j*16 + lr],
                          acc[i][j][rr] * sc);
}

// ---------------------------------------------------------------------------
// in-place row softmax (scale 3 only). grid: (n, nb)
template<typename T>
__global__ __launch_bounds__(256) void softmax_kernel(T* __restrict__ S, int n)
{
    int b = blockIdx.y;
    int row = blockIdx.x;
    T* rp = S + (size_t)b * n * n + (size_t)row * n;
    __shared__ float red[256];
    int t = threadIdx.x;

    float m = -1e30f;
    for (int j = t; j < n; j += 256) m = fmaxf(m, ld1(&rp[j]));
    red[t] = m; __syncthreads();
    for (int s = 128; s > 0; s >>= 1) { if (t < s) red[t] = fmaxf(red[t], red[t + s]); __syncthreads(); }
    m = red[0]; __syncthreads();

    float sum = 0.f;
    for (int j = t; j < n; j += 256) { float e = __expf(ld1(&rp[j]) - m); st1(&rp[j], e); sum += e; }
    red[t] = sum; __syncthreads();
    for (int s = 128; s > 0; s >>= 1) { if (t < s) red[t] += red[t + s]; __syncthreads(); }
    float inv = 1.f / red[0];
    for (int j = t; j < n; j += 256) st1(&rp[j], ld1(&rp[j]) * inv);
}

// ---------------------------------------------------------------------------
// scale-3 O = P(64x64, normalized) V([d][tok]) via MFMA, K=64 single shot.
// grid (128 d-tiles, 1, 4 b). 4 waves, each N-range 32, M=64 full.
__global__ __launch_bounds__(256) void o3_mfma(
    const float* __restrict__ P, const unsigned short* __restrict__ Vb,
    unsigned short* __restrict__ aotp)
{
    const int CH0 = 192;
    int n0 = blockIdx.x * 128;
    int b = blockIdx.z;
    const float* Pb = P + (size_t)b * 4096;
    const unsigned short* V = Vb + (size_t)b * TOK;   // [d=16384][tok=64]

    __shared__ unsigned short As[4096];   // 64x64 bf16, swizzled
    __shared__ unsigned short Bs[8192];   // 128x64 bf16, swizzled

    int t = threadIdx.x, w = t >> 6, lane = t & 63;
    int quad = lane >> 4, lr = lane & 15;
    int wn = w;

    // P fp32 -> bf16 swizzled LDS (write XOR matches read XOR)
    #pragma unroll
    for (int k = 0; k < 2; k++) {
        int u = t + k * 256;
        int row = u >> 3, slot = u & 7;
        const float* pp = &Pb[(row << 6) + (slot << 3)];
        unsigned short tmp[8];
        #pragma unroll
        for (int e = 0; e < 8; e++) tmp[e] = f2bf(pp[e]);
        int off = ((row << 7) + (slot << 4)) ^ ((row & 7) << 4);
        *(uint4*)((char*)As + off) = *(const uint4*)tmp;
    }
    stage64(V + (size_t)n0 * 64, 64, Bs, t);
    __syncthreads();

    f32x4 acc[4][2];
    #pragma unroll
    for (int i = 0; i < 4; i++)
        #pragma unroll
        for (int j = 0; j < 2; j++) acc[i][j] = (f32x4){0.f, 0.f, 0.f, 0.f};

    #pragma unroll
    for (int s = 0; s < 2; s++) {
        bf16x8 af[4], bfr[2];
        #pragma unroll
        for (int i = 0; i < 4; i++) {
            int row = i*16 + lr;
            int off = (row << 7) + (s << 6) + (quad << 4);
            af[i] = *(const bf16x8*)((const char*)As + (off ^ ((row & 7) << 4)));
        }
        #pragma unroll
        for (int j = 0; j < 2; j++) {
            int row = wn*32 + j*16 + lr;
            int off = (row << 7) + (s << 6) + (quad << 4);
            bfr[j] = *(const bf16x8*)((const char*)Bs + (off ^ ((row & 7) << 4)));
        }
        #pragma unroll
        for (int i = 0; i < 4; i++)
            #pragma unroll
            for (int j = 0; j < 2; j++)
                acc[i][j] = __builtin_amdgcn_mfma_f32_16x16x32_bf16(
                    af[i], bfr[j], acc[i][j], 0, 0, 0);
    }

    #pragma unroll
    for (int i = 0; i < 4; i++)
        #pragma unroll
        for (int rr = 0; rr < 4; rr++) {
            int tok = i*16 + quad*4 + rr;
            int oy = tok >> 3, ox = tok & 7;
            #pragma unroll
            for (int j = 0; j < 2; j++) {
                int d = n0 + wn*32 + j*16 + lr;
                int ch = d >> 8;
                int r2 = d & 255;
                int wy = r2 >> 4, wx = r2 & 15;
                int yy = oy * 16 + wy, xx = ox * 16 + wx;
                aotp[((size_t)(b * 130 + yy + 1) * 130 + xx + 1) * CC + CH0 + ch]
                    = f2bf(acc[i][j][rr]);
            }
        }
}

// ---------------------------------------------------------------------------
// BN apply with fused finalize (reads raw sum/sumsq). grid (16384).
__global__ __launch_bounds__(256) void bn_apply_kernel(
    float* __restrict__ z, const float* __restrict__ stats,
    const float* __restrict__ gamma, const float* __restrict__ beta)
{
    size_t i4 = (size_t)blockIdx.x * 256 + threadIdx.x;
    size_t idx = i4 * 4;
    int c = (int)((idx >> 14) & 255);
    const float inv_n = 1.f / (BN * HWP);
    float mean = stats[c] * inv_n;
    float var = stats[CC + c] * inv_n - mean * mean;
    float rstd = rsqrtf(var + 1e-5f);
    float gs = gamma[c] * rstd;
    float gb = beta[c] - mean * gs;
    float4 v = *(float4*)&z[idx];
    v.x = fmaf(v.x, gs, gb); v.y = fmaf(v.y, gs, gb);
    v.z = fmaf(v.z, gs, gb); v.w = fmaf(v.w, gs, gb);
    v.x = v.x >= 0.f ? v.x : 0.2f * v.x;
    v.y = v.y >= 0.f ? v.y : 0.2f * v.y;
    v.z = v.z >= 0.f ? v.z : 0.2f * v.z;
    v.w = v.w >= 0.f ? v.w : 0.2f * v.w;
    *(float4*)&z[idx] = v;
}

// ---------------------------------------------------------------------------
extern "C" void kernel_launch(void* const* d_in, const int* in_sizes, int n_in,
                              void* d_out, int out_size, void* d_ws, size_t ws_size,
                              hipStream_t stream)
{
    const float* x     = (const float*)d_in[0];
    const float* y     = (const float*)d_in[1];
    const float* Wq    = (const float*)d_in[2];
    const float* bq    = (const float*)d_in[3];
    const float* Wk    = (const float*)d_in[4];
    const float* bk    = (const float*)d_in[5];
    const float* Wv    = (const float*)d_in[6];
    const float* bv    = (const float*)d_in[7];
    const float* Wo    = (const float*)d_in[8];
    const float* bo    = (const float*)d_in[9];
    const float* gamma = (const float*)d_in[10];
    const float* beta  = (const float*)d_in[11];
    float* out = (float*)d_out;

    unsigned short* qt    = (unsigned short*)d_ws;
    unsigned short* kt    = qt + (size_t)16777216;
    unsigned short* vt    = kt + (size_t)16777216;
    unsigned short* aotp  = vt + (size_t)16777216;          // padded, 17,305,600 shorts
    unsigned short* Sbf   = aotp + (size_t)17305600;        // 4,194,304 shorts
    unsigned short* wpack = Sbf + (size_t)4194304;          // 589,824 shorts
    unsigned short* Wqkv  = wpack + (size_t)589824;         // 196,608 shorts
    float* stats = (float*)(Wqkv + (size_t)196608);
    float* S3    = stats + 512;
    float* rs0   = S3 + 16384;     // [4][4096]
    float* rs1   = rs0 + 16384;    // [4][1024]
    float* rs2   = rs1 + 4096;     // [4][256]

    // d_out scratch:
    unsigned short* xt = (unsigned short*)d_out;                       // 33.5 MB
    unsigned short* yt = (unsigned short*)((char*)d_out + 33554432);   // 33.5 MB
    float* part = (float*)d_out;          // flash0 partials (xt dead by then)
    float* S2p  = (float*)d_out;          // scale-2 partials (part dead by then)

    dim3 blk(256);

    // zero stats(512)+S3(16384)+rs0(16384)+rs1(4096)+rs2(1024) = 38400 floats
    zero_kernel<<<dim3(150), blk, 0, stream>>>(stats);
    // zero padded aot (halo must be 0; interior fully overwritten later)
    zero4<<<dim3(2048), blk, 0, stream>>>((uint4*)aotp, 2163200);

    nchw_to_nhwc<<<dim3(256, 4, 8), blk, 0, stream>>>(x, y, xt, yt);
    wpack_kernel<<<dim3(256), blk, 0, stream>>>(Wo, wpack);
    wqkv_pack<<<dim3(3), blk, 0, stream>>>(Wq, Wk, Wv, Wqkv);

    proj_gemm<<<dim3(128, 2, 12), blk, 0, stream>>>(
        xt, yt, Wqkv, bq, bk, bv, qt, kt, vt);

    // scale 0: n=4096, D=256, window 2 — fused flash, kv-split x2
    flash0<<<dim3(512), dim3(512), 0, stream>>>(qt, kt, vt, part, rs0);
    combine0f<<<dim3(256, 4), blk, 0, stream>>>(part, rs0, aotp);

    // scale 1: n=1024, D=1024, window 4
    s_gemm_exp<1024, 1024><<<dim3(8, 8, 4), blk, 0, stream>>>(
        qt + (size_t)4 * TOK, kt + (size_t)4 * TOK, Sbf, rs1, 1.f / 32.f);
    o_gemm<1024, 1024, 2, 64><<<dim3(8, 8, 4), blk, 0, stream>>>(
        Sbf, vt + (size_t)4 * TOK, rs1, aotp, 0);

    // scale 2: n=256, D=4096, window 8 — 8-way K-split into d_out scratch
    s2_partial<<<dim3(2, 2, 32), blk, 0, stream>>>(
        qt + (size_t)8 * TOK, kt + (size_t)8 * TOK, S2p);
    s2_finish<<<dim3(256, 4), blk, 0, stream>>>(S2p, Sbf, rs2, 1.f / 64.f);
    o_gemm<256, 4096, 3, 128><<<dim3(32, 2, 4), blk, 0, stream>>>(
        Sbf, vt + (size_t)8 * TOK, rs2, aotp, 0);

    // scale 3: n=64, D=16384, window 16 — MFMA path
    s3_mfma<<<dim3(64), blk, 0, stream>>>(
        qt + (size_t)12 * TOK, kt + (size_t)12 * TOK, S3, 1.f / 128.f);
    softmax_kernel<float><<<dim3(64, 4), blk, 0, stream>>>(S3, 64);
    o3_mfma<<<dim3(128, 1, 4), blk, 0, stream>>>(S3, vt + (size_t)12 * TOK, aotp);

    // conv3x3 (padded, new engine) + fused BN stats, then apply
    conv_gemm<<<dim3(128, 2, 4), blk, 0, stream>>>(aotp, wpack, bo, out, stats);
    bn_apply_kernel<<<dim3(16384), blk, 0, stream>>>(out, stats, gamma, beta);
}